// Round 1
// baseline (967.438 us; speedup 1.0000x reference)
//
#include <hip/hip_runtime.h>
#include <hip/hip_bf16.h>
#include <math.h>

#define S_LEN 2048
#define B_SZ 2
#define DMODEL 1024
#define NH 16
#define DK 64
#define NEGV -1e9f
#define SM_SHIFT 8.0f   // constant softmax shift: exp(s-8); exact (cancels in p/l)

typedef __attribute__((ext_vector_type(8))) short bf16x8;
typedef __attribute__((ext_vector_type(4))) float f32x4;

__device__ inline short f2bf(float f) {
    __hip_bfloat16 h = __float2bfloat16(f);
    return __builtin_bit_cast(short, h);
}
__device__ inline float bf2f(short s) {
    unsigned int u = ((unsigned int)(unsigned short)s) << 16;
    return __builtin_bit_cast(float, u);
}
__device__ inline f32x4 mfma16(bf16x8 a, bf16x8 b, f32x4 c) {
    return __builtin_amdgcn_mfma_f32_16x16x32_bf16(a, b, c, 0, 0, 0);
}

// ---------------------------------------------------------------------------
// fp32 -> bf16 elementwise convert (x)
// ---------------------------------------------------------------------------
__global__ __launch_bounds__(256) void cvt_bf16(const float* __restrict__ in,
                                                short* __restrict__ out, int n4) {
    int i = blockIdx.x * 256 + threadIdx.x;
    if (i < n4) {
        float4 v = *(const float4*)&in[(size_t)i * 4];
        short4 o = { f2bf(v.x), f2bf(v.y), f2bf(v.z), f2bf(v.w) };
        *(short4*)&out[(size_t)i * 4] = o;
    }
}

// ---------------------------------------------------------------------------
// Weight transpose+convert: W fp32 [K=1024][N=1024] -> Wt bf16 [N][K]
// ---------------------------------------------------------------------------
__global__ __launch_bounds__(256) void wtrans(const float* __restrict__ W,
                                              short* __restrict__ Wt) {
    __shared__ __align__(16) short T[64][72];
    const int k0 = blockIdx.x * 64, n0 = blockIdx.y * 64;
    const int tid = threadIdx.x;
#pragma unroll
    for (int i = 0; i < 4; ++i) {
        int idx = tid + i * 256;          // 64 k-rows x 16 float4
        int kr = idx >> 4, n4 = idx & 15;
        float4 v = *(const float4*)&W[(size_t)(k0 + kr) * DMODEL + n0 + n4 * 4];
        short4 o = { f2bf(v.x), f2bf(v.y), f2bf(v.z), f2bf(v.w) };
        *(short4*)&T[kr][n4 * 4] = o;
    }
    __syncthreads();
#pragma unroll
    for (int i = 0; i < 2; ++i) {
        int idx = tid + i * 256;          // 64 n-rows x 8 chunks(8 shorts)
        int n = idx >> 3, c8 = idx & 7;
        short v[8];
#pragma unroll
        for (int j = 0; j < 8; ++j) v[j] = T[c8 * 8 + j][n];
        *(int4*)&Wt[(size_t)(n0 + n) * DMODEL + k0 + c8 * 8] = *(int4*)v;
    }
}

// ---------------------------------------------------------------------------
// V transpose (per head): Vb bf16 [b][s][1024] -> Vt bf16 [bh][64 d][2048 s]
// ---------------------------------------------------------------------------
__global__ __launch_bounds__(256) void vtrans(const short* __restrict__ Vb,
                                              short* __restrict__ Vt) {
    __shared__ __align__(16) short T[64][72];
    const int bh = blockIdx.y, b = bh >> 4, h = bh & 15;
    const int s0 = blockIdx.x * 64;
    const int tid = threadIdx.x;
#pragma unroll
    for (int i = 0; i < 2; ++i) {
        int idx = tid + i * 256;          // 64 token-rows x 8 chunks
        int r = idx >> 3, c8 = idx & 7;
        *(int4*)&T[r][c8 * 8] =
            *(const int4*)&Vb[((size_t)(b * S_LEN + s0 + r)) * DMODEL + h * DK + c8 * 8];
    }
    __syncthreads();
#pragma unroll
    for (int i = 0; i < 2; ++i) {
        int idx = tid + i * 256;          // 64 d-rows x 8 chunks
        int d = idx >> 3, c8 = idx & 7;
        short v[8];
#pragma unroll
        for (int j = 0; j < 8; ++j) v[j] = T[c8 * 8 + j][d];
        *(int4*)&Vt[((size_t)(bh * DK + d)) * S_LEN + s0 + c8 * 8] = *(int4*)v;
    }
}

// ---------------------------------------------------------------------------
// bf16 MFMA GEMM: C[M,N] = A[M,K] @ Bt[N,K]^T + bias. 64x64 tile, BK=64.
// 256 thr = 4 waves (2x2), each wave 32x32 via 2x2 mfma_16x16x32 frags.
// ---------------------------------------------------------------------------
template <bool OUT_BF16>
__global__ __launch_bounds__(256) void gemm_bf(
    const short* __restrict__ A, const short* __restrict__ Bt,
    const float* __restrict__ bias, void* __restrict__ Cout,
    int M, int N, int K) {
    __shared__ __align__(16) short As[64][72];
    __shared__ __align__(16) short Bs[64][72];
    const int row0 = blockIdx.y * 64, col0 = blockIdx.x * 64;
    const int tid = threadIdx.x;
    const int w = tid >> 6, l = tid & 63, lm = l & 15, quad = l >> 4;
    const int wm = (w >> 1) * 32, wn = (w & 1) * 32;
    f32x4 acc[2][2] = {};

    for (int k0 = 0; k0 < K; k0 += 64) {
        __syncthreads();
#pragma unroll
        for (int i = 0; i < 2; ++i) {
            int idx = tid + i * 256;
            int r = idx >> 3, c8 = idx & 7;
            *(int4*)&As[r][c8 * 8] = *(const int4*)&A[(size_t)(row0 + r) * K + k0 + c8 * 8];
            *(int4*)&Bs[r][c8 * 8] = *(const int4*)&Bt[(size_t)(col0 + r) * K + k0 + c8 * 8];
        }
        __syncthreads();
#pragma unroll
        for (int kc = 0; kc < 2; ++kc) {
            bf16x8 a0 = *(const bf16x8*)&As[wm + lm][kc * 32 + quad * 8];
            bf16x8 a1 = *(const bf16x8*)&As[wm + 16 + lm][kc * 32 + quad * 8];
            bf16x8 b0 = *(const bf16x8*)&Bs[wn + lm][kc * 32 + quad * 8];
            bf16x8 b1 = *(const bf16x8*)&Bs[wn + 16 + lm][kc * 32 + quad * 8];
            acc[0][0] = mfma16(a0, b0, acc[0][0]);
            acc[0][1] = mfma16(a0, b1, acc[0][1]);
            acc[1][0] = mfma16(a1, b0, acc[1][0]);
            acc[1][1] = mfma16(a1, b1, acc[1][1]);
        }
    }
#pragma unroll
    for (int mi = 0; mi < 2; ++mi)
#pragma unroll
        for (int ni = 0; ni < 2; ++ni)
#pragma unroll
            for (int r = 0; r < 4; ++r) {
                int row = row0 + wm + mi * 16 + quad * 4 + r;
                int col = col0 + wn + ni * 16 + lm;
                float v = acc[mi][ni][r] + bias[col];
                if (OUT_BF16)
                    ((short*)Cout)[(size_t)row * N + col] = f2bf(v);
                else
                    ((float*)Cout)[(size_t)row * N + col] = v;
            }
}

// ---------------------------------------------------------------------------
// first nonpad token index per batch
// ---------------------------------------------------------------------------
__global__ __launch_bounds__(256) void fnp_scan(const int* __restrict__ tok,
                                                int* __restrict__ fnp) {
    __shared__ int mn;
    const int b = blockIdx.x;
    if (threadIdx.x == 0) mn = S_LEN;
    __syncthreads();
    int loc = S_LEN;
    for (int s = threadIdx.x; s < S_LEN; s += 256)
        if (tok[b * S_LEN + s] != 0) loc = min(loc, s);
    atomicMin(&mn, loc);
    __syncthreads();
    if (threadIdx.x == 0) fnp[b] = mn;
}

// ---------------------------------------------------------------------------
// Single-pass flash (no-max softmax): p = exp(s - SM_SHIFT) is exact after
// division by l = sum(p). Writes unnormalized p (fp32) to attn band,
// accumulates l per row (one end-of-row shuffle reduce, none per tile),
// accumulates O = sum(p*V) via MFMA, writes ctx = O/l. Lrow stores l for
// the attn_fix rescale pass. Replaces flash_ml + flash_pb.
// ---------------------------------------------------------------------------
__global__ __launch_bounds__(256) void flash_fused(
    const short* __restrict__ Qb, const short* __restrict__ Kb,
    const short* __restrict__ Vt, const int* __restrict__ tok,
    float* __restrict__ attn, float* __restrict__ Lrow, short* __restrict__ ctxb) {
    const int bh = blockIdx.y, b = bh >> 4, h = bh & 15;
    const int qt = blockIdx.x, q0 = qt * 64;
    const int tid = threadIdx.x;
    const int w = tid >> 6, l = tid & 63, lm = l & 15, quad = l >> 4;
    __shared__ __align__(16) short Qs[64][72];
    __shared__ __align__(16) short Ks[64][72];
    __shared__ __align__(16) short Vs[64][72];
    __shared__ __align__(16) short Ps[64][72];
    __shared__ float padf[64];

#pragma unroll
    for (int i = 0; i < 2; ++i) {
        int idx = tid + i * 256;
        int r = idx >> 3, c8 = idx & 7;
        *(int4*)&Qs[r][c8 * 8] =
            *(const int4*)&Qb[((size_t)(b * S_LEN + q0 + r)) * DMODEL + h * DK + c8 * 8];
    }

    float lsum[4] = {0.f, 0.f, 0.f, 0.f};
    f32x4 oacc[4] = {};

    for (int kt = 0; kt <= qt; ++kt) {
        __syncthreads();
#pragma unroll
        for (int i = 0; i < 2; ++i) {
            int idx = tid + i * 256;
            int r = idx >> 3, c8 = idx & 7;
            *(int4*)&Ks[r][c8 * 8] =
                *(const int4*)&Kb[((size_t)(b * S_LEN + kt * 64 + r)) * DMODEL + h * DK + c8 * 8];
            *(int4*)&Vs[r][c8 * 8] =
                *(const int4*)&Vt[((size_t)(bh * DK + r)) * S_LEN + kt * 64 + c8 * 8];
        }
        if (tid < 64) padf[tid] = (tok[b * S_LEN + kt * 64 + tid] == 0) ? 1.f : 0.f;
        __syncthreads();

#pragma unroll
        for (int nt = 0; nt < 4; ++nt) {
            f32x4 acc = {0.f, 0.f, 0.f, 0.f};
#pragma unroll
            for (int kc = 0; kc < 2; ++kc) {
                bf16x8 a = *(const bf16x8*)&Qs[w * 16 + lm][kc * 32 + quad * 8];
                bf16x8 bb = *(const bf16x8*)&Ks[nt * 16 + lm][kc * 32 + quad * 8];
                acc = mfma16(a, bb, acc);
            }
            int kcol = kt * 64 + nt * 16 + lm;
            bool pad = padf[nt * 16 + lm] != 0.f;
#pragma unroll
            for (int r = 0; r < 4; ++r) {
                int qrow = q0 + w * 16 + quad * 4 + r;
                bool msk = pad || (kcol > qrow);
                float p = msk ? 0.f : __expf(acc[r] * 0.125f - SM_SHIFT);
                attn[((size_t)bh * S_LEN + qrow) * S_LEN + kcol] = p;
                lsum[r] += p;
                Ps[w * 16 + quad * 4 + r][nt * 16 + lm] = f2bf(p);
            }
        }
        // P (written by this wave's own lanes) -> A-frags; V -> B-frags
#pragma unroll
        for (int kc = 0; kc < 2; ++kc) {
            bf16x8 a = *(const bf16x8*)&Ps[w * 16 + lm][kc * 32 + quad * 8];
#pragma unroll
            for (int dt = 0; dt < 4; ++dt) {
                bf16x8 bv = *(const bf16x8*)&Vs[dt * 16 + lm][kc * 32 + quad * 8];
                oacc[dt] = mfma16(a, bv, oacc[dt]);
            }
        }
    }

    // single end-of-row reduce of l across the 16 lm lanes sharing each row
#pragma unroll
    for (int off = 1; off < 16; off <<= 1)
#pragma unroll
        for (int r = 0; r < 4; ++r) lsum[r] += __shfl_xor(lsum[r], off);

    if (lm == 0) {
#pragma unroll
        for (int r = 0; r < 4; ++r)
            Lrow[(size_t)bh * S_LEN + q0 + w * 16 + quad * 4 + r] = lsum[r];
    }

    float inv[4];
#pragma unroll
    for (int r = 0; r < 4; ++r) inv[r] = 1.f / lsum[r];   // inf if fully masked
#pragma unroll
    for (int dt = 0; dt < 4; ++dt)
#pragma unroll
        for (int r = 0; r < 4; ++r) {
            int qrow = q0 + w * 16 + quad * 4 + r;
            ctxb[((size_t)(b * S_LEN + qrow)) * DMODEL + h * DK + dt * 16 + lm] =
                f2bf(oacc[dt][r] * inv[r]);   // NaN rows fixed by fix_fullmask
        }
}

// ---------------------------------------------------------------------------
// attn fixup: scale causal band by 1/l, zero the strict-upper region.
// Replaces fill_upper + normalization. Fully-masked rows (l=0) produce NaN
// in the band; fix_fullmask overwrites those rows afterward.
// ---------------------------------------------------------------------------
__global__ __launch_bounds__(256) void attn_fix(const float* __restrict__ Lrow,
                                                float* __restrict__ attn) {
    const int qt = blockIdx.x, bh = blockIdx.y;
    __shared__ float sinv[64];
    if (threadIdx.x < 64)
        sinv[threadIdx.x] = 1.f / Lrow[(size_t)bh * S_LEN + qt * 64 + threadIdx.x];
    __syncthreads();
    const int ce4 = (qt + 1) * 16;                 // band end in float4 units
    float* base = attn + ((size_t)bh * S_LEN + qt * 64) * S_LEN;
    for (int i = threadIdx.x; i < 64 * (S_LEN / 4); i += 256) {
        int row = i >> 9, c4 = i & 511;
        float4* p = (float4*)&base[(size_t)row * S_LEN + c4 * 4];
        if (c4 < ce4) {
            float s = sinv[row];
            float4 v = *p;
            v.x *= s; v.y *= s; v.z *= s; v.w *= s;
            *p = v;
        } else {
            float4 z = {0.f, 0.f, 0.f, 0.f};
            *p = z;
        }
    }
}

// ---------------------------------------------------------------------------
// Fully-masked rows (q < first-nonpad): attn row = 1/2048 (all heads),
// ctx row = mean(V). Rare/usually-empty; blocks early-out.
// ---------------------------------------------------------------------------
__global__ __launch_bounds__(256) void fix_fullmask(
    const int* __restrict__ fnp, const short* __restrict__ Vb,
    float* __restrict__ attn, short* __restrict__ ctxb) {
    const int b = blockIdx.x >> 11, q = blockIdx.x & 2047;
    if (q >= fnp[b]) return;
    const float u = 1.f / (float)S_LEN;
    float4 uu = {u, u, u, u};
    for (int i = threadIdx.x; i < NH * (S_LEN / 4); i += 256) {
        int h = i / (S_LEN / 4), c4 = i % (S_LEN / 4);
        *(float4*)&attn[(((size_t)(b * NH + h) * S_LEN + q)) * S_LEN + c4 * 4] = uu;
    }
    for (int d = threadIdx.x; d < DMODEL; d += 256) {
        float sv = 0.f;
        for (int s = 0; s < S_LEN; ++s)
            sv += bf2f(Vb[((size_t)(b * S_LEN + s)) * DMODEL + d]);
        ctxb[((size_t)(b * S_LEN + q)) * DMODEL + d] = f2bf(sv * u);
    }
}

extern "C" void kernel_launch(void* const* d_in, const int* in_sizes, int n_in,
                              void* d_out, int out_size, void* d_ws, size_t ws_size,
                              hipStream_t stream) {
    const float* x  = (const float*)d_in[0];
    const int*  tok = (const int*)d_in[1];
    const float* wq = (const float*)d_in[2];
    const float* bq = (const float*)d_in[3];
    const float* wk = (const float*)d_in[4];
    const float* bk = (const float*)d_in[5];
    const float* wv = (const float*)d_in[6];
    const float* bv = (const float*)d_in[7];
    const float* wo = (const float*)d_in[8];
    const float* bo = (const float*)d_in[9];

    float* out  = (float*)d_out;
    float* attn = out + (size_t)B_SZ * S_LEN * DMODEL;

    const size_t NTOK = (size_t)B_SZ * S_LEN;        // 4096
    const size_t NE   = NTOK * DMODEL;               // 4,194,304
    short* xb   = (short*)d_ws;
    short* Wt   = xb + NE;                           // 4 x 1024x1024
    short* Qb   = Wt + 4 * (size_t)DMODEL * DMODEL;
    short* Kb   = Qb + NE;
    short* Vb   = Kb + NE;
    short* Vt   = Vb + NE;
    short* ctxb = Vt + NE;
    float* Lrow = (float*)(ctxb + NE);
    int*   fnp  = (int*)(Lrow + (size_t)B_SZ * NH * S_LEN);

    dim3 blk(256);

    cvt_bf16<<<dim3((int)(NE / 4 / 256)), blk, 0, stream>>>(x, xb, (int)(NE / 4));
    wtrans<<<dim3(16, 16), blk, 0, stream>>>(wq, Wt + 0 * (size_t)DMODEL * DMODEL);
    wtrans<<<dim3(16, 16), blk, 0, stream>>>(wk, Wt + 1 * (size_t)DMODEL * DMODEL);
    wtrans<<<dim3(16, 16), blk, 0, stream>>>(wv, Wt + 2 * (size_t)DMODEL * DMODEL);
    wtrans<<<dim3(16, 16), blk, 0, stream>>>(wo, Wt + 3 * (size_t)DMODEL * DMODEL);

    dim3 g_gemm(DMODEL / 64, (int)(NTOK / 64));      // (16, 64)
    gemm_bf<true><<<g_gemm, blk, 0, stream>>>(xb, Wt + 0 * (size_t)DMODEL * DMODEL, bq, Qb,
                                              (int)NTOK, DMODEL, DMODEL);
    gemm_bf<true><<<g_gemm, blk, 0, stream>>>(xb, Wt + 1 * (size_t)DMODEL * DMODEL, bk, Kb,
                                              (int)NTOK, DMODEL, DMODEL);
    gemm_bf<true><<<g_gemm, blk, 0, stream>>>(xb, Wt + 2 * (size_t)DMODEL * DMODEL, bv, Vb,
                                              (int)NTOK, DMODEL, DMODEL);

    vtrans<<<dim3(S_LEN / 64, B_SZ * NH), blk, 0, stream>>>(Vb, Vt);
    fnp_scan<<<dim3(B_SZ), blk, 0, stream>>>(tok, fnp);

    flash_fused<<<dim3(S_LEN / 64, B_SZ * NH), blk, 0, stream>>>(Qb, Kb, Vt, tok,
                                                                 attn, Lrow, ctxb);
    attn_fix<<<dim3(S_LEN / 64, B_SZ * NH), blk, 0, stream>>>(Lrow, attn);
    fix_fullmask<<<dim3(B_SZ * S_LEN), blk, 0, stream>>>(fnp, Vb, attn, ctxb);

    gemm_bf<false><<<g_gemm, blk, 0, stream>>>(ctxb, Wt + 3 * (size_t)DMODEL * DMODEL, bo, out,
                                               (int)NTOK, DMODEL, DMODEL);
}

// Round 2
// 836.977 us; speedup vs baseline: 1.1559x; 1.1559x over previous
//
#include <hip/hip_runtime.h>
#include <hip/hip_bf16.h>
#include <math.h>

#define S_LEN 2048
#define B_SZ 2
#define DMODEL 1024
#define NH 16
#define DK 64
#define QKVN 3072          // fused QKV output width
#define SM_SHIFT 8.0f      // constant softmax shift: exp(s-8); exact after /l

typedef __attribute__((ext_vector_type(8))) short bf16x8;
typedef __attribute__((ext_vector_type(4))) float f32x4;

__device__ inline short f2bf(float f) {
    __hip_bfloat16 h = __float2bfloat16(f);
    return __builtin_bit_cast(short, h);
}
__device__ inline float bf2f(short s) {
    unsigned int u = ((unsigned int)(unsigned short)s) << 16;
    return __builtin_bit_cast(float, u);
}
__device__ inline f32x4 mfma16(bf16x8 a, bf16x8 b, f32x4 c) {
    return __builtin_amdgcn_mfma_f32_16x16x32_bf16(a, b, c, 0, 0, 0);
}
// async global->LDS, 16B per lane; LDS dest = wave-uniform base + lane*16
__device__ inline void gl_lds16(const void* g, void* l) {
    __builtin_amdgcn_global_load_lds(
        (const __attribute__((address_space(1))) void*)g,
        (__attribute__((address_space(3))) void*)l, 16, 0, 0);
}

// ---------------------------------------------------------------------------
// fp32 -> bf16 elementwise convert (x)
// ---------------------------------------------------------------------------
__global__ __launch_bounds__(256) void cvt_bf16(const float* __restrict__ in,
                                                short* __restrict__ out, int n4) {
    int i = blockIdx.x * 256 + threadIdx.x;
    if (i < n4) {
        float4 v = *(const float4*)&in[(size_t)i * 4];
        short4 o = { f2bf(v.x), f2bf(v.y), f2bf(v.z), f2bf(v.w) };
        *(short4*)&out[(size_t)i * 4] = o;
    }
}

// ---------------------------------------------------------------------------
// Weight transpose+convert: W fp32 [K=1024][N=1024] -> Wt bf16 [N][K]
// ---------------------------------------------------------------------------
__global__ __launch_bounds__(256) void wtrans(const float* __restrict__ W,
                                              short* __restrict__ Wt) {
    __shared__ __align__(16) short T[64][72];
    const int k0 = blockIdx.x * 64, n0 = blockIdx.y * 64;
    const int tid = threadIdx.x;
#pragma unroll
    for (int i = 0; i < 4; ++i) {
        int idx = tid + i * 256;          // 64 k-rows x 16 float4
        int kr = idx >> 4, n4 = idx & 15;
        float4 v = *(const float4*)&W[(size_t)(k0 + kr) * DMODEL + n0 + n4 * 4];
        short4 o = { f2bf(v.x), f2bf(v.y), f2bf(v.z), f2bf(v.w) };
        *(short4*)&T[kr][n4 * 4] = o;
    }
    __syncthreads();
#pragma unroll
    for (int i = 0; i < 2; ++i) {
        int idx = tid + i * 256;          // 64 n-rows x 8 chunks(8 shorts)
        int n = idx >> 3, c8 = idx & 7;
        short v[8];
#pragma unroll
        for (int j = 0; j < 8; ++j) v[j] = T[c8 * 8 + j][n];
        *(int4*)&Wt[(size_t)(n0 + n) * DMODEL + k0 + c8 * 8] = *(int4*)v;
    }
}

// ---------------------------------------------------------------------------
// concat bias [bq|bk|bv] -> cbias[3072]
// ---------------------------------------------------------------------------
__global__ __launch_bounds__(256) void cbias_cat(const float* __restrict__ bq,
                                                 const float* __restrict__ bk,
                                                 const float* __restrict__ bv,
                                                 float* __restrict__ cb) {
    int i = blockIdx.x * 256 + threadIdx.x;
    if (i < QKVN)
        cb[i] = i < 1024 ? bq[i] : (i < 2048 ? bk[i - 1024] : bv[i - 2048]);
}

// ---------------------------------------------------------------------------
// Fused QKV GEMM (m97 structure): C[M,3072] = A[M,1024] @ Wt3[3072,1024]^T
// + cbias, bf16 out. 128x128 tile, BK=64, global_load_lds width-16 staging.
// 4 waves (2x2), each wave 64x64 via 4x4 mfma_16x16x32 frags.
// ---------------------------------------------------------------------------
__global__ __launch_bounds__(256) void gemm_qkv(
    const short* __restrict__ A, const short* __restrict__ Bt,
    const float* __restrict__ bias, short* __restrict__ C,
    int M, int N, int K) {
    __shared__ __align__(16) short As[128][64];   // linear: required by gl_lds16
    __shared__ __align__(16) short Bs[128][64];
    const int row0 = blockIdx.y * 128, col0 = blockIdx.x * 128;
    const int tid = threadIdx.x;
    const int w = tid >> 6, l = tid & 63, lm = l & 15, quad = l >> 4;
    const int wm = (w >> 1) * 64, wn = (w & 1) * 64;
    const int lrow = tid >> 3, lc8 = tid & 7;     // 32 rows x 8 chunks per issue
    f32x4 acc[4][4] = {};

    for (int k0 = 0; k0 < K; k0 += 64) {
        __syncthreads();
#pragma unroll
        for (int i = 0; i < 4; ++i)               // A: 128 rows, 32/issue
            gl_lds16(&A[(size_t)(row0 + i * 32 + lrow) * K + k0 + lc8 * 8],
                     (short*)As + (i * 32 + w * 8) * 64);
#pragma unroll
        for (int i = 0; i < 4; ++i)               // B: 128 rows
            gl_lds16(&Bt[(size_t)(col0 + i * 32 + lrow) * K + k0 + lc8 * 8],
                     (short*)Bs + (i * 32 + w * 8) * 64);
        __syncthreads();                          // drains vmcnt before barrier
#pragma unroll
        for (int kc = 0; kc < 2; ++kc) {
            bf16x8 a[4], b[4];
#pragma unroll
            for (int mi = 0; mi < 4; ++mi)
                a[mi] = *(const bf16x8*)&As[wm + mi * 16 + lm][kc * 32 + quad * 8];
#pragma unroll
            for (int ni = 0; ni < 4; ++ni)
                b[ni] = *(const bf16x8*)&Bs[wn + ni * 16 + lm][kc * 32 + quad * 8];
#pragma unroll
            for (int mi = 0; mi < 4; ++mi)
#pragma unroll
                for (int ni = 0; ni < 4; ++ni)
                    acc[mi][ni] = mfma16(a[mi], b[ni], acc[mi][ni]);
        }
    }
#pragma unroll
    for (int mi = 0; mi < 4; ++mi)
#pragma unroll
        for (int ni = 0; ni < 4; ++ni) {
            int col = col0 + wn + ni * 16 + lm;
            float bs = bias[col];
#pragma unroll
            for (int r = 0; r < 4; ++r) {
                int row = row0 + wm + mi * 16 + quad * 4 + r;
                C[(size_t)row * N + col] = f2bf(acc[mi][ni][r] + bs);
            }
        }
}

// ---------------------------------------------------------------------------
// V transpose (per head): QKV bf16 [b][s][3072] (V at col 2048) ->
// Vt bf16 [bh][64 d][2048 s]
// ---------------------------------------------------------------------------
__global__ __launch_bounds__(256) void vtrans(const short* __restrict__ QKV,
                                              short* __restrict__ Vt) {
    __shared__ __align__(16) short T[64][72];
    const int bh = blockIdx.y, b = bh >> 4, h = bh & 15;
    const int s0 = blockIdx.x * 64;
    const int tid = threadIdx.x;
#pragma unroll
    for (int i = 0; i < 2; ++i) {
        int idx = tid + i * 256;          // 64 token-rows x 8 chunks
        int r = idx >> 3, c8 = idx & 7;
        *(int4*)&T[r][c8 * 8] =
            *(const int4*)&QKV[((size_t)(b * S_LEN + s0 + r)) * QKVN + 2048 + h * DK + c8 * 8];
    }
    __syncthreads();
#pragma unroll
    for (int i = 0; i < 2; ++i) {
        int idx = tid + i * 256;          // 64 d-rows x 8 chunks
        int d = idx >> 3, c8 = idx & 7;
        short v[8];
#pragma unroll
        for (int j = 0; j < 8; ++j) v[j] = T[c8 * 8 + j][d];
        *(int4*)&Vt[((size_t)(bh * DK + d)) * S_LEN + s0 + c8 * 8] = *(int4*)v;
    }
}

// ---------------------------------------------------------------------------
// bf16 MFMA GEMM (64x64 tile) for the output projection.
// ---------------------------------------------------------------------------
__global__ __launch_bounds__(256) void gemm_out(
    const short* __restrict__ A, const short* __restrict__ Bt,
    const float* __restrict__ bias, float* __restrict__ Cout,
    int M, int N, int K) {
    __shared__ __align__(16) short As[64][72];
    __shared__ __align__(16) short Bs[64][72];
    const int row0 = blockIdx.y * 64, col0 = blockIdx.x * 64;
    const int tid = threadIdx.x;
    const int w = tid >> 6, l = tid & 63, lm = l & 15, quad = l >> 4;
    const int wm = (w >> 1) * 32, wn = (w & 1) * 32;
    f32x4 acc[2][2] = {};

    for (int k0 = 0; k0 < K; k0 += 64) {
        __syncthreads();
#pragma unroll
        for (int i = 0; i < 2; ++i) {
            int idx = tid + i * 256;
            int r = idx >> 3, c8 = idx & 7;
            *(int4*)&As[r][c8 * 8] = *(const int4*)&A[(size_t)(row0 + r) * K + k0 + c8 * 8];
            *(int4*)&Bs[r][c8 * 8] = *(const int4*)&Bt[(size_t)(col0 + r) * K + k0 + c8 * 8];
        }
        __syncthreads();
#pragma unroll
        for (int kc = 0; kc < 2; ++kc) {
            bf16x8 a0 = *(const bf16x8*)&As[wm + lm][kc * 32 + quad * 8];
            bf16x8 a1 = *(const bf16x8*)&As[wm + 16 + lm][kc * 32 + quad * 8];
            bf16x8 b0 = *(const bf16x8*)&Bs[wn + lm][kc * 32 + quad * 8];
            bf16x8 b1 = *(const bf16x8*)&Bs[wn + 16 + lm][kc * 32 + quad * 8];
            acc[0][0] = mfma16(a0, b0, acc[0][0]);
            acc[0][1] = mfma16(a0, b1, acc[0][1]);
            acc[1][0] = mfma16(a1, b0, acc[1][0]);
            acc[1][1] = mfma16(a1, b1, acc[1][1]);
        }
    }
#pragma unroll
    for (int mi = 0; mi < 2; ++mi)
#pragma unroll
        for (int ni = 0; ni < 2; ++ni)
#pragma unroll
            for (int r = 0; r < 4; ++r) {
                int row = row0 + wm + mi * 16 + quad * 4 + r;
                int col = col0 + wn + ni * 16 + lm;
                Cout[(size_t)row * N + col] = acc[mi][ni][r] + bias[col];
            }
}

// ---------------------------------------------------------------------------
// first nonpad token index per batch
// ---------------------------------------------------------------------------
__global__ __launch_bounds__(256) void fnp_scan(const int* __restrict__ tok,
                                                int* __restrict__ fnp) {
    __shared__ int mn;
    const int b = blockIdx.x;
    if (threadIdx.x == 0) mn = S_LEN;
    __syncthreads();
    int loc = S_LEN;
    for (int s = threadIdx.x; s < S_LEN; s += 256)
        if (tok[b * S_LEN + s] != 0) loc = min(loc, s);
    atomicMin(&mn, loc);
    __syncthreads();
    if (threadIdx.x == 0) fnp[b] = mn;
}

// ---------------------------------------------------------------------------
// Pass A (no-max softmax): l = sum over causal band of exp(s - 8).
// No running max, no per-tile reductions; one 4-step shuffle at end of row.
// ---------------------------------------------------------------------------
__global__ __launch_bounds__(256) void flash_lsum(
    const short* __restrict__ QKV, const int* __restrict__ tok,
    float* __restrict__ Lrow) {
    const int bh = blockIdx.y, b = bh >> 4, h = bh & 15;
    const int qt = blockIdx.x, q0 = qt * 64;
    const int tid = threadIdx.x;
    const int w = tid >> 6, l = tid & 63, lm = l & 15, quad = l >> 4;
    __shared__ __align__(16) short Qs[64][72];
    __shared__ __align__(16) short Ks[64][72];
    __shared__ float padf[64];

#pragma unroll
    for (int i = 0; i < 2; ++i) {
        int idx = tid + i * 256;
        int r = idx >> 3, c8 = idx & 7;
        *(int4*)&Qs[r][c8 * 8] =
            *(const int4*)&QKV[((size_t)(b * S_LEN + q0 + r)) * QKVN + h * DK + c8 * 8];
    }

    float lsum[4] = {0.f, 0.f, 0.f, 0.f};

    for (int kt = 0; kt <= qt; ++kt) {
        __syncthreads();
#pragma unroll
        for (int i = 0; i < 2; ++i) {
            int idx = tid + i * 256;
            int r = idx >> 3, c8 = idx & 7;
            *(int4*)&Ks[r][c8 * 8] =
                *(const int4*)&QKV[((size_t)(b * S_LEN + kt * 64 + r)) * QKVN + 1024 + h * DK + c8 * 8];
        }
        if (tid < 64) padf[tid] = (tok[b * S_LEN + kt * 64 + tid] == 0) ? 1.f : 0.f;
        __syncthreads();

#pragma unroll
        for (int nt = 0; nt < 4; ++nt) {
            f32x4 acc = {0.f, 0.f, 0.f, 0.f};
#pragma unroll
            for (int kc = 0; kc < 2; ++kc) {
                bf16x8 a = *(const bf16x8*)&Qs[w * 16 + lm][kc * 32 + quad * 8];
                bf16x8 bb = *(const bf16x8*)&Ks[nt * 16 + lm][kc * 32 + quad * 8];
                acc = mfma16(a, bb, acc);
            }
            int kcol = kt * 64 + nt * 16 + lm;
            bool pad = padf[nt * 16 + lm] != 0.f;
#pragma unroll
            for (int r = 0; r < 4; ++r) {
                int qrow = q0 + w * 16 + quad * 4 + r;
                bool msk = pad || (kcol > qrow);
                lsum[r] += msk ? 0.f : __expf(acc[r] * 0.125f - SM_SHIFT);
            }
        }
    }

#pragma unroll
    for (int off = 1; off < 16; off <<= 1)
#pragma unroll
        for (int r = 0; r < 4; ++r) lsum[r] += __shfl_xor(lsum[r], off);

    if (lm == 0) {
#pragma unroll
        for (int r = 0; r < 4; ++r)
            Lrow[(size_t)bh * S_LEN + q0 + w * 16 + quad * 4 + r] = lsum[r];
    }
}

// ---------------------------------------------------------------------------
// Pass B: p = exp(s-8)/l, write fp32 attn (causal band, normalized, once),
// P -> LDS bf16 -> MFMA P@V -> ctx bf16.
// ---------------------------------------------------------------------------
__global__ __launch_bounds__(256) void flash_pb(
    const short* __restrict__ QKV, const short* __restrict__ Vt,
    const int* __restrict__ tok, const float* __restrict__ Lrow,
    float* __restrict__ attn, short* __restrict__ ctxb) {
    const int bh = blockIdx.y, b = bh >> 4, h = bh & 15;
    const int qt = blockIdx.x, q0 = qt * 64;
    const int tid = threadIdx.x;
    const int w = tid >> 6, l = tid & 63, lm = l & 15, quad = l >> 4;
    __shared__ __align__(16) short Qs[64][72];
    __shared__ __align__(16) short Ks[64][72];
    __shared__ __align__(16) short Vs[64][72];
    __shared__ __align__(16) short Ps[64][72];
    __shared__ float padf[64];

#pragma unroll
    for (int i = 0; i < 2; ++i) {
        int idx = tid + i * 256;
        int r = idx >> 3, c8 = idx & 7;
        *(int4*)&Qs[r][c8 * 8] =
            *(const int4*)&QKV[((size_t)(b * S_LEN + q0 + r)) * QKVN + h * DK + c8 * 8];
    }

    float linv[4];
#pragma unroll
    for (int r = 0; r < 4; ++r)
        linv[r] = 1.f / Lrow[(size_t)bh * S_LEN + q0 + w * 16 + quad * 4 + r];

    f32x4 oacc[4] = {};

    for (int kt = 0; kt <= qt; ++kt) {
        __syncthreads();
#pragma unroll
        for (int i = 0; i < 2; ++i) {
            int idx = tid + i * 256;
            int r = idx >> 3, c8 = idx & 7;
            *(int4*)&Ks[r][c8 * 8] =
                *(const int4*)&QKV[((size_t)(b * S_LEN + kt * 64 + r)) * QKVN + 1024 + h * DK + c8 * 8];
            *(int4*)&Vs[r][c8 * 8] =
                *(const int4*)&Vt[((size_t)(bh * DK + r)) * S_LEN + kt * 64 + c8 * 8];
        }
        if (tid < 64) padf[tid] = (tok[b * S_LEN + kt * 64 + tid] == 0) ? 1.f : 0.f;
        __syncthreads();

#pragma unroll
        for (int nt = 0; nt < 4; ++nt) {
            f32x4 acc = {0.f, 0.f, 0.f, 0.f};
#pragma unroll
            for (int kc = 0; kc < 2; ++kc) {
                bf16x8 a = *(const bf16x8*)&Qs[w * 16 + lm][kc * 32 + quad * 8];
                bf16x8 bb = *(const bf16x8*)&Ks[nt * 16 + lm][kc * 32 + quad * 8];
                acc = mfma16(a, bb, acc);
            }
            int kcol = kt * 64 + nt * 16 + lm;
            bool pad = padf[nt * 16 + lm] != 0.f;
#pragma unroll
            for (int r = 0; r < 4; ++r) {
                int qrow = q0 + w * 16 + quad * 4 + r;
                bool msk = pad || (kcol > qrow);
                float p = msk ? 0.f : __expf(acc[r] * 0.125f - SM_SHIFT) * linv[r];
                attn[((size_t)bh * S_LEN + qrow) * S_LEN + kcol] = p;
                Ps[w * 16 + quad * 4 + r][nt * 16 + lm] = f2bf(p);
            }
        }
        // P (written by this wave's own lanes) -> A-frags; V -> B-frags
#pragma unroll
        for (int kc = 0; kc < 2; ++kc) {
            bf16x8 a = *(const bf16x8*)&Ps[w * 16 + lm][kc * 32 + quad * 8];
#pragma unroll
            for (int dt = 0; dt < 4; ++dt) {
                bf16x8 bv = *(const bf16x8*)&Vs[dt * 16 + lm][kc * 32 + quad * 8];
                oacc[dt] = mfma16(a, bv, oacc[dt]);
            }
        }
    }

#pragma unroll
    for (int dt = 0; dt < 4; ++dt)
#pragma unroll
        for (int r = 0; r < 4; ++r) {
            int qrow = q0 + w * 16 + quad * 4 + r;
            ctxb[((size_t)(b * S_LEN + qrow)) * DMODEL + h * DK + dt * 16 + lm] =
                f2bf(oacc[dt][r]);
        }
}

// ---------------------------------------------------------------------------
// Zero the strict-upper (causal-masked) tiles of attn.
// ---------------------------------------------------------------------------
__global__ __launch_bounds__(256) void fill_upper(float* __restrict__ attn) {
    const int qt = blockIdx.x, bh = blockIdx.y;
    const int ce = (qt + 1) * 64;
    const int n = S_LEN - ce;
    if (n <= 0) return;
    const int n4 = n >> 2;
    float4 z = {0.f, 0.f, 0.f, 0.f};
    float* base = attn + ((size_t)bh * S_LEN + qt * 64) * S_LEN;
    for (int i = threadIdx.x; i < 64 * n4; i += 256) {
        int row = i / n4, c = i % n4;
        *(float4*)&base[(size_t)row * S_LEN + ce + c * 4] = z;
    }
}

// ---------------------------------------------------------------------------
// Fully-masked rows (q < first-nonpad): attn row = 1/2048 (all heads),
// ctx row = mean(V). Rare/usually-empty; blocks early-out.
// ---------------------------------------------------------------------------
__global__ __launch_bounds__(256) void fix_fullmask(
    const int* __restrict__ fnp, const short* __restrict__ QKV,
    float* __restrict__ attn, short* __restrict__ ctxb) {
    const int b = blockIdx.x >> 11, q = blockIdx.x & 2047;
    if (q >= fnp[b]) return;
    const float u = 1.f / (float)S_LEN;
    float4 uu = {u, u, u, u};
    for (int i = threadIdx.x; i < NH * (S_LEN / 4); i += 256) {
        int h = i / (S_LEN / 4), c4 = i % (S_LEN / 4);
        *(float4*)&attn[(((size_t)(b * NH + h) * S_LEN + q)) * S_LEN + c4 * 4] = uu;
    }
    for (int d = threadIdx.x; d < DMODEL; d += 256) {
        float sv = 0.f;
        for (int s = 0; s < S_LEN; ++s)
            sv += bf2f(QKV[((size_t)(b * S_LEN + s)) * QKVN + 2048 + d]);
        ctxb[((size_t)(b * S_LEN + q)) * DMODEL + d] = f2bf(sv * u);
    }
}

extern "C" void kernel_launch(void* const* d_in, const int* in_sizes, int n_in,
                              void* d_out, int out_size, void* d_ws, size_t ws_size,
                              hipStream_t stream) {
    const float* x  = (const float*)d_in[0];
    const int*  tok = (const int*)d_in[1];
    const float* wq = (const float*)d_in[2];
    const float* bq = (const float*)d_in[3];
    const float* wk = (const float*)d_in[4];
    const float* bk = (const float*)d_in[5];
    const float* wv = (const float*)d_in[6];
    const float* bv = (const float*)d_in[7];
    const float* wo = (const float*)d_in[8];
    const float* bo = (const float*)d_in[9];

    float* out  = (float*)d_out;
    float* attn = out + (size_t)B_SZ * S_LEN * DMODEL;

    const size_t NTOK = (size_t)B_SZ * S_LEN;        // 4096
    const size_t NE   = NTOK * DMODEL;               // 4,194,304
    const size_t WSZ  = (size_t)DMODEL * DMODEL;     // 1M elements
    short* xb    = (short*)d_ws;                     // [4096][1024]
    short* Wt3   = xb + NE;                          // [3072][1024]
    short* Wto   = Wt3 + 3 * WSZ;                    // [1024][1024]
    short* QKVb  = Wto + WSZ;                        // [4096][3072]
    short* Vt    = QKVb + NTOK * QKVN;               // [32][64][2048]
    short* ctxb  = Vt + NE;                          // [4096][1024]
    float* cbias = (float*)(ctxb + NE);              // [3072]
    float* Lrow  = cbias + QKVN;                     // [32][2048]
    int*   fnp   = (int*)(Lrow + (size_t)B_SZ * NH * S_LEN);

    dim3 blk(256);

    cvt_bf16<<<dim3((int)(NE / 4 / 256)), blk, 0, stream>>>(x, xb, (int)(NE / 4));
    wtrans<<<dim3(16, 16), blk, 0, stream>>>(wq, Wt3 + 0 * WSZ);
    wtrans<<<dim3(16, 16), blk, 0, stream>>>(wk, Wt3 + 1 * WSZ);
    wtrans<<<dim3(16, 16), blk, 0, stream>>>(wv, Wt3 + 2 * WSZ);
    wtrans<<<dim3(16, 16), blk, 0, stream>>>(wo, Wto);
    cbias_cat<<<dim3(QKVN / 256), blk, 0, stream>>>(bq, bk, bv, cbias);

    gemm_qkv<<<dim3(QKVN / 128, (int)(NTOK / 128)), blk, 0, stream>>>(
        xb, Wt3, cbias, QKVb, (int)NTOK, QKVN, DMODEL);

    vtrans<<<dim3(S_LEN / 64, B_SZ * NH), blk, 0, stream>>>(QKVb, Vt);
    fnp_scan<<<dim3(B_SZ), blk, 0, stream>>>(tok, fnp);

    flash_lsum<<<dim3(S_LEN / 64, B_SZ * NH), blk, 0, stream>>>(QKVb, tok, Lrow);
    flash_pb<<<dim3(S_LEN / 64, B_SZ * NH), blk, 0, stream>>>(QKVb, Vt, tok, Lrow,
                                                              attn, ctxb);
    fill_upper<<<dim3(S_LEN / 64, B_SZ * NH), blk, 0, stream>>>(attn);
    fix_fullmask<<<dim3(B_SZ * S_LEN), blk, 0, stream>>>(fnp, QKVb, attn, ctxb);

    gemm_out<<<dim3(DMODEL / 64, (int)(NTOK / 64)), blk, 0, stream>>>(
        ctxb, Wto, bo, out, (int)NTOK, DMODEL, DMODEL);
}